// Round 1
// baseline (326.674 us; speedup 1.0000x reference)
//
#include <hip/hip_runtime.h>
#include <math.h>

// TopKRouter: x[16384,2048] fp32, W[64,2048] fp32
// out: [0..32767] top2 indices (as float), [32768..65535] gates, [65536] aux loss
#define NTOK 16384
#define DDIM 2048
#define NEXP 64
#define BM 32
#define BK 64
#define NBLOCKS (NTOK / BM)   // 512

__global__ __launch_bounds__(256) void router_kernel(
    const float* __restrict__ x, const float* __restrict__ W,
    float* __restrict__ out, float* __restrict__ part)
{
    __shared__ float xs[BK][BM + 2];    // [k][m], pad to keep banks spread
    __shared__ float wsm[BK][NEXP];     // [k][e]
    __shared__ float lgt[BM][NEXP + 1]; // [m][e]: logits, then probs
    __shared__ float cnt[NEXP];

    const int tid = threadIdx.x;
    const int tx = tid & 15;   // expert group: experts 4*tx .. 4*tx+3
    const int ty = tid >> 4;   // token group: tokens 2*ty, 2*ty+1
    const int m0 = blockIdx.x * BM;

    if (tid < NEXP) cnt[tid] = 0.0f;

    float acc00 = 0.f, acc01 = 0.f, acc02 = 0.f, acc03 = 0.f;
    float acc10 = 0.f, acc11 = 0.f, acc12 = 0.f, acc13 = 0.f;

    for (int kc = 0; kc < DDIM; kc += BK) {
        __syncthreads();
        // stage x tile: 32 rows x 16 float4 (512 float4, 2/thread)
        #pragma unroll
        for (int i = 0; i < 2; ++i) {
            int q = tid + i * 256;
            int row = q >> 4, col = q & 15;
            float4 v = *(const float4*)&x[(size_t)(m0 + row) * DDIM + kc + col * 4];
            xs[col * 4 + 0][row] = v.x;
            xs[col * 4 + 1][row] = v.y;
            xs[col * 4 + 2][row] = v.z;
            xs[col * 4 + 3][row] = v.w;
        }
        // stage W tile: 64 rows x 16 float4 (1024 float4, 4/thread)
        #pragma unroll
        for (int i = 0; i < 4; ++i) {
            int q = tid + i * 256;
            int e = q >> 4, col = q & 15;
            float4 v = *(const float4*)&W[(size_t)e * DDIM + kc + col * 4];
            wsm[col * 4 + 0][e] = v.x;
            wsm[col * 4 + 1][e] = v.y;
            wsm[col * 4 + 2][e] = v.z;
            wsm[col * 4 + 3][e] = v.w;
        }
        __syncthreads();
        #pragma unroll 16
        for (int k = 0; k < BK; ++k) {
            float2 xv = *(const float2*)&xs[k][ty * 2];
            float4 wv = *(const float4*)&wsm[k][tx * 4];
            acc00 = fmaf(xv.x, wv.x, acc00);
            acc01 = fmaf(xv.x, wv.y, acc01);
            acc02 = fmaf(xv.x, wv.z, acc02);
            acc03 = fmaf(xv.x, wv.w, acc03);
            acc10 = fmaf(xv.y, wv.x, acc10);
            acc11 = fmaf(xv.y, wv.y, acc11);
            acc12 = fmaf(xv.y, wv.z, acc12);
            acc13 = fmaf(xv.y, wv.w, acc13);
        }
    }

    // write logits to LDS
    lgt[ty * 2 + 0][tx * 4 + 0] = acc00;
    lgt[ty * 2 + 0][tx * 4 + 1] = acc01;
    lgt[ty * 2 + 0][tx * 4 + 2] = acc02;
    lgt[ty * 2 + 0][tx * 4 + 3] = acc03;
    lgt[ty * 2 + 1][tx * 4 + 0] = acc10;
    lgt[ty * 2 + 1][tx * 4 + 1] = acc11;
    lgt[ty * 2 + 1][tx * 4 + 2] = acc12;
    lgt[ty * 2 + 1][tx * 4 + 3] = acc13;
    __syncthreads();

    // epilogue: 8 threads per token (32 tokens x 8 lanes = 256)
    const int m = tid >> 3;
    const int j = tid & 7;
    float l[8];
    #pragma unroll
    for (int i = 0; i < 8; ++i) l[i] = lgt[m][j * 8 + i];

    // group max
    float mx = l[0];
    #pragma unroll
    for (int i = 1; i < 8; ++i) mx = fmaxf(mx, l[i]);
    #pragma unroll
    for (int off = 1; off < 8; off <<= 1) mx = fmaxf(mx, __shfl_xor(mx, off, 8));

    // exp, partial sum, local top-2 (ties -> lower index, matching lax.top_k)
    float ev[8];
    float zs = 0.f;
    float v1 = -INFINITY, v2 = -INFINITY;
    int i1 = 0, i2 = 0;
    #pragma unroll
    for (int i = 0; i < 8; ++i) {
        ev[i] = __expf(l[i] - mx);
        zs += ev[i];
        int e = j * 8 + i;
        if (l[i] > v1)      { v2 = v1; i2 = i1; v1 = l[i]; i1 = e; }
        else if (l[i] > v2) { v2 = l[i]; i2 = e; }
    }
    #pragma unroll
    for (int off = 1; off < 8; off <<= 1) zs += __shfl_xor(zs, off, 8);

    // merge top-2 pairs across the 8 lanes (butterfly; order = value desc, index asc)
    #pragma unroll
    for (int off = 1; off < 8; off <<= 1) {
        float ov1 = __shfl_xor(v1, off, 8);
        int   oi1 = __shfl_xor(i1, off, 8);
        float ov2 = __shfl_xor(v2, off, 8);
        int   oi2 = __shfl_xor(i2, off, 8);
        bool afirst = (v1 > ov1) || (v1 == ov1 && i1 < oi1);
        if (afirst) {
            bool t = (v2 > ov1) || (v2 == ov1 && i2 < oi1);
            v2 = t ? v2 : ov1;
            i2 = t ? i2 : oi1;
        } else {
            bool t = (ov2 > v1) || (ov2 == v1 && oi2 < i1);
            v2 = t ? ov2 : v1;
            i2 = t ? oi2 : i1;
            v1 = ov1;
            i1 = oi1;
        }
    }

    const float invz = 1.0f / zs;
    if (j == 0) {
        // v1 == mx exactly, so p1 = 1/Z
        float p1 = invz;
        float p2 = __expf(v2 - mx) * invz;
        float sden = p1 + p2 + 1e-9f;
        int tok = m0 + m;
        out[tok * 2 + 0] = (float)i1;
        out[tok * 2 + 1] = (float)i2;
        out[32768 + tok * 2 + 0] = p1 / sden;
        out[32768 + tok * 2 + 1] = p2 / sden;
        atomicAdd(&cnt[i1], 1.0f);
        atomicAdd(&cnt[i2], 1.0f);
    }

    // probs back into lgt (each thread overwrites only slots it owns)
    #pragma unroll
    for (int i = 0; i < 8; ++i) lgt[m][j * 8 + i] = ev[i] * invz;
    __syncthreads();

    // per-block partials: counts[64], prob column sums[64] -> no global atomics
    if (tid < NEXP) {
        float s = 0.f;
        #pragma unroll 8
        for (int mm = 0; mm < BM; ++mm) s += lgt[mm][tid];
        part[(size_t)blockIdx.x * 128 + tid] = cnt[tid];
        part[(size_t)blockIdx.x * 128 + 64 + tid] = s;
    }
}

__global__ void finalize_kernel(const float* __restrict__ part,
                                float* __restrict__ out)
{
    __shared__ float buf[128];
    const int t = threadIdx.x; // 128 threads
    float s = 0.f;
    for (int b = 0; b < NBLOCKS; ++b) s += part[(size_t)b * 128 + t];
    buf[t] = s;
    __syncthreads();
    if (t == 0) {
        float aux = 0.f;
        #pragma unroll
        for (int e = 0; e < NEXP; ++e) {
            float frac_tokens = buf[e] / (float)(NTOK * 2);      // counts / (B*S*K)
            float avg_prob = buf[64 + e] / (float)NTOK;          // mean router prob
            aux += frac_tokens * avg_prob;
        }
        out[65536] = 0.01f * (float)NEXP * aux;
    }
}

extern "C" void kernel_launch(void* const* d_in, const int* in_sizes, int n_in,
                              void* d_out, int out_size, void* d_ws, size_t ws_size,
                              hipStream_t stream) {
    const float* x = (const float*)d_in[0];   // [4,4096,2048]
    const float* W = (const float*)d_in[1];   // [64,2048]
    float* out = (float*)d_out;               // 65537 floats
    float* part = (float*)d_ws;               // 512*128 floats = 256 KB

    router_kernel<<<NBLOCKS, 256, 0, stream>>>(x, W, out, part);
    finalize_kernel<<<1, 128, 0, stream>>>(part, out);
}

// Round 2
// 284.692 us; speedup vs baseline: 1.1475x; 1.1475x over previous
//
#include <hip/hip_runtime.h>
#include <math.h>

// TopKRouter: x[16384,2048] fp32, W[64,2048] fp32
// out: [0..32767] top2 indices (as float), [32768..65535] gates, [65536] aux
#define NTOK 16384
#define DDIM 2048
#define NEXP 64
#define BM 64                 // tokens per block
#define BK 64                 // k per staging chunk
#define NBLK (NTOK / BM)      // 256 blocks
#define XPAD 2                // xs row pad (float2-aligned, 2-way conflicts = free)

// ws float layout: [0..127] global accum (counts[64], probsums[64]); [128..] Wt[k][e]
#define WT_FOFF 128

__global__ __launch_bounds__(512) void prep_kernel(const float* __restrict__ W,
                                                   float* __restrict__ ws) {
    int idx = blockIdx.x * 512 + threadIdx.x;   // grid 256 -> 131072 = 2048*64
    int k = idx >> 6, e = idx & 63;
    ws[WT_FOFF + idx] = W[(size_t)e * DDIM + k];   // Wt[k][e]
    if (idx < 128) ws[idx] = 0.0f;                 // zero accumulators (block 0)
}

__global__ void zero_kernel(float* __restrict__ ws) {
    if (threadIdx.x < 128) ws[threadIdx.x] = 0.0f;
}

template <bool UWT>
__global__ __launch_bounds__(512) void router_kernel(
    const float* __restrict__ x, const float* __restrict__ wsrc,
    float* __restrict__ accg, float* __restrict__ out)
{
    __shared__ float xs[2][BM][BK + XPAD];    // 2 x 64 x 66 floats = 33.8 KB
    __shared__ float lgt[BM][NEXP + 1];       // 64 x 65 = 16.6 KB
    __shared__ float cnt[NEXP];

    const int tid = threadIdx.x;
    const int lane = tid & 63;                              // token within tile
    const int wv = __builtin_amdgcn_readfirstlane(tid >> 6); // wave id 0..7 (uniform)
    const int m0 = blockIdx.x * BM;

    if (tid < NEXP) cnt[tid] = 0.0f;

    // staging mapping: p = tid + i*512 -> tok = p>>4, col = p&15 (16 float4 per row)
    const int tok0 = tid >> 4, col0 = tid & 15;

    float acc[8];
    #pragma unroll
    for (int j = 0; j < 8; ++j) acc[j] = 0.0f;

    // prologue: load tile 0 into regs
    float4 r0 = *(const float4*)&x[(size_t)(m0 + tok0) * DDIM + col0 * 4];
    float4 r1 = *(const float4*)&x[(size_t)(m0 + tok0 + 32) * DDIM + col0 * 4];

    int buf = 0;
    for (int kc = 0; kc < DDIM; kc += BK) {
        // write staged regs -> LDS (float2 stores: 8B-aligned with XPAD=2)
        *(float2*)&xs[buf][tok0][col0 * 4 + 0] = make_float2(r0.x, r0.y);
        *(float2*)&xs[buf][tok0][col0 * 4 + 2] = make_float2(r0.z, r0.w);
        *(float2*)&xs[buf][tok0 + 32][col0 * 4 + 0] = make_float2(r1.x, r1.y);
        *(float2*)&xs[buf][tok0 + 32][col0 * 4 + 2] = make_float2(r1.z, r1.w);
        __syncthreads();

        // prefetch next tile (overlaps compute below)
        if (kc + BK < DDIM) {
            r0 = *(const float4*)&x[(size_t)(m0 + tok0) * DDIM + kc + BK + col0 * 4];
            r1 = *(const float4*)&x[(size_t)(m0 + tok0 + 32) * DDIM + kc + BK + col0 * 4];
        }

        // compute: lane = token, 8 experts per wave via wave-uniform (scalar) W
        #pragma unroll 8
        for (int g = 0; g < BK / 2; ++g) {
            float2 xv = *(const float2*)&xs[buf][lane][2 * g];
            if (UWT) {
                // Wt[k][e]: 8 consecutive floats per k -> s_load_dwordx4 x2
                const float* wr = wsrc + (size_t)(kc + 2 * g) * NEXP + wv * 8;
                #pragma unroll
                for (int j = 0; j < 8; ++j)
                    acc[j] = fmaf(xv.x, wr[j], acc[j]);
                #pragma unroll
                for (int j = 0; j < 8; ++j)
                    acc[j] = fmaf(xv.y, wr[NEXP + j], acc[j]);
            } else {
                // direct W[e][k]: strided uniform float2 loads
                const float* wr = wsrc + (size_t)(wv * 8) * DDIM + kc + 2 * g;
                #pragma unroll
                for (int j = 0; j < 8; ++j) {
                    float2 wj = *(const float2*)&wr[(size_t)j * DDIM];
                    acc[j] = fmaf(xv.x, wj.x, fmaf(xv.y, wj.y, acc[j]));
                }
            }
        }
        buf ^= 1;
    }

    // logits -> LDS
    #pragma unroll
    for (int j = 0; j < 8; ++j) lgt[lane][wv * 8 + j] = acc[j];
    __syncthreads();

    // epilogue: 8 threads per token (64 tokens x 8 lanes = 512 threads)
    const int m = tid >> 3;
    const int j = tid & 7;
    float l[8];
    #pragma unroll
    for (int i = 0; i < 8; ++i) l[i] = lgt[m][j * 8 + i];

    float mx = l[0];
    #pragma unroll
    for (int i = 1; i < 8; ++i) mx = fmaxf(mx, l[i]);
    #pragma unroll
    for (int off = 1; off < 8; off <<= 1) mx = fmaxf(mx, __shfl_xor(mx, off, 8));

    float ev[8];
    float zs = 0.f;
    float v1 = -INFINITY, v2 = -INFINITY;
    int i1 = 0, i2 = 0;
    #pragma unroll
    for (int i = 0; i < 8; ++i) {
        ev[i] = __expf(l[i] - mx);
        zs += ev[i];
        int e = j * 8 + i;
        if (l[i] > v1)      { v2 = v1; i2 = i1; v1 = l[i]; i1 = e; }
        else if (l[i] > v2) { v2 = l[i]; i2 = e; }
    }
    #pragma unroll
    for (int off = 1; off < 8; off <<= 1) zs += __shfl_xor(zs, off, 8);

    // merge top-2 across 8 lanes (value desc, index asc on ties = lax.top_k)
    #pragma unroll
    for (int off = 1; off < 8; off <<= 1) {
        float ov1 = __shfl_xor(v1, off, 8);
        int   oi1 = __shfl_xor(i1, off, 8);
        float ov2 = __shfl_xor(v2, off, 8);
        int   oi2 = __shfl_xor(i2, off, 8);
        bool afirst = (v1 > ov1) || (v1 == ov1 && i1 < oi1);
        if (afirst) {
            bool t = (v2 > ov1) || (v2 == ov1 && i2 < oi1);
            v2 = t ? v2 : ov1;
            i2 = t ? i2 : oi1;
        } else {
            bool t = (ov2 > v1) || (ov2 == v1 && oi2 < i1);
            v2 = t ? ov2 : v1;
            i2 = t ? oi2 : i1;
            v1 = ov1;
            i1 = oi1;
        }
    }

    const float invz = 1.0f / zs;
    if (j == 0) {
        float p1 = invz;                      // v1 == mx exactly
        float p2 = __expf(v2 - mx) * invz;
        float sden = p1 + p2 + 1e-9f;
        int tok = m0 + m;
        out[tok * 2 + 0] = (float)i1;
        out[tok * 2 + 1] = (float)i2;
        out[32768 + tok * 2 + 0] = p1 / sden;
        out[32768 + tok * 2 + 1] = p2 / sden;
        atomicAdd(&cnt[i1], 1.0f);
        atomicAdd(&cnt[i2], 1.0f);
    }

    // probs back into lgt (own slots only)
    #pragma unroll
    for (int i = 0; i < 8; ++i) lgt[m][j * 8 + i] = ev[i] * invz;
    __syncthreads();

    // per-block partials -> global atomics (accg zeroed by prep)
    if (tid < 128) {
        int e = tid & 63, h = tid >> 6;
        float s = 0.f;
        #pragma unroll 8
        for (int mm = 0; mm < BM / 2; ++mm) s += lgt[h * 32 + mm][e];
        atomicAdd(&accg[64 + e], s);
    }
    if (tid < NEXP) atomicAdd(&accg[tid], cnt[tid]);
}

__global__ void finalize_kernel(const float* __restrict__ accg,
                                float* __restrict__ out)
{
    int t = threadIdx.x;   // 64 threads
    float c = accg[t];
    float p = accg[64 + t];
    float term = (c / (float)(NTOK * 2)) * (p / (float)NTOK);
    #pragma unroll
    for (int off = 1; off < 64; off <<= 1) term += __shfl_xor(term, off, 64);
    if (t == 0) out[65536] = 0.01f * (float)NEXP * term;
}

extern "C" void kernel_launch(void* const* d_in, const int* in_sizes, int n_in,
                              void* d_out, int out_size, void* d_ws, size_t ws_size,
                              hipStream_t stream) {
    const float* x = (const float*)d_in[0];   // [4,4096,2048]
    const float* W = (const float*)d_in[1];   // [64,2048]
    float* out = (float*)d_out;               // 65537 floats
    float* ws = (float*)d_ws;

    const size_t need = (size_t)(WT_FOFF + DDIM * NEXP) * sizeof(float);
    if (ws_size >= need) {
        prep_kernel<<<256, 512, 0, stream>>>(W, ws);
        router_kernel<true><<<NBLK, 512, 0, stream>>>(x, ws + WT_FOFF, ws, out);
    } else {
        zero_kernel<<<1, 128, 0, stream>>>(ws);
        router_kernel<false><<<NBLK, 512, 0, stream>>>(x, W, ws, out);
    }
    finalize_kernel<<<1, 64, 0, stream>>>(ws, out);
}